// Round 1
// baseline (1073.372 us; speedup 1.0000x reference)
//
#include <hip/hip_runtime.h>

#define HIDDEN  1024
#define NHEADS  16
#define HDIM    64
#define BATCH   32
#define PREV    4095
#define S_TOTAL 4096
#define NSPLIT  8
#define SCHUNK  (S_TOTAL / NSPLIT)   // 512
#define SCALING 0.125f               // 64^-0.5
#define FMAX    3.402823466e38f

// ws layout (float offsets)
#define Q_OFF    0
#define K_OFF    32768
#define V_OFF    65536
#define ATTN_OFF 98304
#define PM_OFF   131072              // 512*8
#define PL_OFF   135168              // 512*8
#define PACC_OFF 139264              // 512*8*64
// total floats: 401408 (~1.6 MB)

__global__ __launch_bounds__(256) void init_bias(
    const float* __restrict__ bq, const float* __restrict__ bk,
    const float* __restrict__ bv, const float* __restrict__ bo,
    float* __restrict__ q, float* __restrict__ k, float* __restrict__ v,
    float* __restrict__ out) {
  int i = blockIdx.x * 256 + threadIdx.x;   // 0..32767
  int o = i & (HIDDEN - 1);
  q[i] = bq[o]; k[i] = bk[o]; v[i] = bv[o]; out[i] = bo[o];
}

// out[b][o] += sum_k x[b][k] * W[o][k]   (x @ W.T), k-split via gridDim.z
__device__ __forceinline__ void proj_body(const float* __restrict__ x,
                                          const float* __restrict__ W,
                                          float* __restrict__ out) {
  int t  = threadIdx.x;
  int o  = blockIdx.x * 64 + (t & 63);
  int bg = __builtin_amdgcn_readfirstlane(t >> 6);   // wave-uniform 0..3
  int kr = HIDDEN / gridDim.z;
  int k0 = blockIdx.z * kr;
  const float4* wr = (const float4*)(W + (size_t)o * HIDDEN + k0);
  float acc[8];
#pragma unroll
  for (int j = 0; j < 8; ++j) acc[j] = 0.f;
  int n4 = kr >> 2;
  for (int i = 0; i < n4; ++i) {
    float4 w4 = wr[i];
#pragma unroll
    for (int j = 0; j < 8; ++j) {
      // (bg*8+j) and k0,i are wave-uniform -> scalar loads
      const float4* xr = (const float4*)(x + (size_t)(bg * 8 + j) * HIDDEN + k0);
      float4 x4 = xr[i];
      acc[j] = fmaf(w4.x, x4.x, acc[j]);
      acc[j] = fmaf(w4.y, x4.y, acc[j]);
      acc[j] = fmaf(w4.z, x4.z, acc[j]);
      acc[j] = fmaf(w4.w, x4.w, acc[j]);
    }
  }
#pragma unroll
  for (int j = 0; j < 8; ++j)
    unsafeAtomicAdd(&out[(size_t)(bg * 8 + j) * HIDDEN + o], acc[j]);
}

__global__ __launch_bounds__(256) void proj_qkv(
    const float* __restrict__ xq, const float* __restrict__ Wq, float* outq,
    const float* __restrict__ xk, const float* __restrict__ Wk, float* outk,
    const float* __restrict__ xv, const float* __restrict__ Wv, float* outv) {
  const float* x; const float* W; float* out;
  if (blockIdx.y == 0)      { x = xq; W = Wq; out = outq; }
  else if (blockIdx.y == 1) { x = xk; W = Wk; out = outk; }
  else                      { x = xv; W = Wv; out = outv; }
  proj_body(x, W, out);
}

__global__ __launch_bounds__(256) void proj_one(
    const float* __restrict__ x, const float* __restrict__ W, float* out) {
  proj_body(x, W, out);
}

__global__ __launch_bounds__(256) void attn_decode(
    const float* __restrict__ prev_key, const float* __restrict__ prev_value,
    const float* __restrict__ q_ws, const float* __restrict__ k_ws,
    const float* __restrict__ v_ws, const int* __restrict__ order,
    const int* __restrict__ mask, float* __restrict__ part_m,
    float* __restrict__ part_l, float* __restrict__ part_acc) {
  int split = blockIdx.x;           // 0..7
  int head  = blockIdx.y;           // 0..511 = b*16+h
  int b = head >> 4, h = head & 15;
  int t = threadIdx.x;
  int bo = order[b];
  int s0 = split * SCHUNK;

  __shared__ float q_sh[HDIM];
  __shared__ float sc[SCHUNK];
  __shared__ float red_m[4];
  __shared__ float red_l[4];
  __shared__ float vred[4][HDIM];

  if (t < HDIM) q_sh[t] = q_ws[(size_t)b * HIDDEN + h * HDIM + t];
  __syncthreads();

  const float4* q4 = (const float4*)q_sh;
  // ---- scores: thread t owns rows t and t+256 ----
  for (int r = t; r < SCHUNK; r += 256) {
    int s = s0 + r;
    const float4* krow = (s < PREV)
        ? (const float4*)(prev_key + ((size_t)(bo * NHEADS + h) * PREV + s) * HDIM)
        : (const float4*)(k_ws + (size_t)b * HIDDEN + h * HDIM);
    float dot = 0.f;
#pragma unroll
    for (int j = 0; j < 16; ++j) {
      float4 kv = krow[j];
      float4 qv = q4[j];
      dot = fmaf(kv.x, qv.x, dot);
      dot = fmaf(kv.y, qv.y, dot);
      dot = fmaf(kv.z, qv.z, dot);
      dot = fmaf(kv.w, qv.w, dot);
    }
    sc[r] = dot * SCALING - FMAX * (float)mask[s];
  }
  __syncthreads();

  // ---- block max ----
  float m = -FMAX;
  for (int r = t; r < SCHUNK; r += 256) m = fmaxf(m, sc[r]);
#pragma unroll
  for (int off = 32; off >= 1; off >>= 1) m = fmaxf(m, __shfl_xor(m, off));
  int wid = t >> 6, lane = t & 63;
  if (lane == 0) red_m[wid] = m;
  __syncthreads();
  m = fmaxf(fmaxf(red_m[0], red_m[1]), fmaxf(red_m[2], red_m[3]));

  // ---- exp + row-sum ----
  float lp = 0.f;
  for (int r = t; r < SCHUNK; r += 256) {
    float e = __expf(sc[r] - m);
    sc[r] = e;
    lp += e;
  }
#pragma unroll
  for (int off = 32; off >= 1; off >>= 1) lp += __shfl_xor(lp, off);
  if (lane == 0) red_l[wid] = lp;
  __syncthreads();
  float lb = (red_l[0] + red_l[1]) + (red_l[2] + red_l[3]);

  // ---- V accumulate: wave `wid` owns 128 rows, lane = d (coalesced) ----
  float acc = 0.f;
  const float* vbase = prev_value + (size_t)(bo * NHEADS + h) * PREV * HDIM;
  int r0 = wid * 128;
#pragma unroll 4
  for (int r = r0; r < r0 + 128; ++r) {
    int s = s0 + r;
    const float* vrow = (s < PREV) ? (vbase + (size_t)s * HDIM)
                                   : (v_ws + (size_t)b * HIDDEN + h * HDIM);
    acc = fmaf(sc[r], vrow[lane], acc);
  }
  vred[wid][lane] = acc;
  __syncthreads();
  if (t < HDIM) {
    float tot = (vred[0][t] + vred[1][t]) + (vred[2][t] + vred[3][t]);
    part_acc[((size_t)head * NSPLIT + split) * HDIM + t] = tot;
  }
  if (t == 0) {
    part_m[head * NSPLIT + split] = m;
    part_l[head * NSPLIT + split] = lb;
  }
}

__global__ __launch_bounds__(64) void attn_combine(
    const float* __restrict__ part_m, const float* __restrict__ part_l,
    const float* __restrict__ part_acc, float* __restrict__ attn) {
  int head = blockIdx.x;
  int d = threadIdx.x;
  float m = -FMAX;
#pragma unroll
  for (int i = 0; i < NSPLIT; ++i) m = fmaxf(m, part_m[head * NSPLIT + i]);
  float L = 0.f, o = 0.f;
#pragma unroll
  for (int i = 0; i < NSPLIT; ++i) {
    float w = __expf(part_m[head * NSPLIT + i] - m);
    L = fmaf(w, part_l[head * NSPLIT + i], L);
    o = fmaf(w, part_acc[((size_t)head * NSPLIT + i) * HDIM + d], o);
  }
  int b = head >> 4, h = head & 15;
  attn[(size_t)b * HIDDEN + h * HDIM + d] = o / L;
}

extern "C" void kernel_launch(void* const* d_in, const int* in_sizes, int n_in,
                              void* d_out, int out_size, void* d_ws, size_t ws_size,
                              hipStream_t stream) {
  const float* qx    = (const float*)d_in[0];
  const float* kx    = (const float*)d_in[1];
  const float* vx    = (const float*)d_in[2];
  const int*   mask  = (const int*)d_in[3];
  const int*   order = (const int*)d_in[4];
  const float* pk    = (const float*)d_in[5];
  const float* pv    = (const float*)d_in[6];
  const float* Wq    = (const float*)d_in[7];
  const float* bq    = (const float*)d_in[8];
  const float* Wk    = (const float*)d_in[9];
  const float* bk    = (const float*)d_in[10];
  const float* Wv    = (const float*)d_in[11];
  const float* bv    = (const float*)d_in[12];
  const float* Wo    = (const float*)d_in[13];
  const float* bo    = (const float*)d_in[14];
  float* out = (float*)d_out;
  float* ws  = (float*)d_ws;

  float* q_ws    = ws + Q_OFF;
  float* k_ws    = ws + K_OFF;
  float* v_ws    = ws + V_OFF;
  float* attn_ws = ws + ATTN_OFF;
  float* pm      = ws + PM_OFF;
  float* pl      = ws + PL_OFF;
  float* pacc    = ws + PACC_OFF;

  // 1. bias init (ws + d_out are poisoned before every call)
  hipLaunchKernelGGL(init_bias, dim3(128), dim3(256), 0, stream,
                     bq, bk, bv, bo, q_ws, k_ws, v_ws, out);
  // 2. QKV projections (k-split=8, atomic accumulate)
  hipLaunchKernelGGL(proj_qkv, dim3(16, 3, 8), dim3(256), 0, stream,
                     qx, Wq, q_ws, kx, Wk, k_ws, vx, Wv, v_ws);
  // 3. flash-decode attention over 8 S-splits
  hipLaunchKernelGGL(attn_decode, dim3(NSPLIT, 512), dim3(256), 0, stream,
                     pk, pv, q_ws, k_ws, v_ws, order, mask, pm, pl, pacc);
  // 4. merge splits
  hipLaunchKernelGGL(attn_combine, dim3(512), dim3(64), 0, stream,
                     pm, pl, pacc, attn_ws);
  // 5. output projection (k-split=16, atomic accumulate onto bias)
  hipLaunchKernelGGL(proj_one, dim3(16, 1, 16), dim3(256), 0, stream,
                     attn_ws, Wo, out);
}

// Round 2
// 1035.024 us; speedup vs baseline: 1.0371x; 1.0371x over previous
//
#include <hip/hip_runtime.h>

#define HIDDEN  1024
#define NHEADS  16
#define HDIM    64
#define BATCH   32
#define PREV    4095
#define S_TOTAL 4096
#define NSPLIT  8
#define SCHUNK  (S_TOTAL / NSPLIT)   // 512
#define SCALING 0.125f               // 64^-0.5
#define FMAX    3.402823466e38f

// ws layout (float offsets)
#define WT_OFF   0                   // 4 transposed 1024x1024 weights
#define Q_OFF    4194304
#define K_OFF    4227072
#define V_OFF    4259840
#define ATTN_OFF 4292608
#define PM_OFF   4325376             // 512*8
#define PL_OFF   4329472             // 512*8
#define PACC_OFF 4333568             // 512*8*64
// end: 4595712 floats (~18.4 MB) << ws_size (~2.1 GB)

__global__ __launch_bounds__(256) void init_bias(
    const float* __restrict__ bq, const float* __restrict__ bk,
    const float* __restrict__ bv, const float* __restrict__ bo,
    float* __restrict__ q, float* __restrict__ k, float* __restrict__ v,
    float* __restrict__ out) {
  int i = blockIdx.x * 256 + threadIdx.x;   // 0..32767
  int o = i & (HIDDEN - 1);
  q[i] = bq[o]; k[i] = bk[o]; v[i] = bv[o]; out[i] = bo[o];
}

// WT[k][o] = W[o][k], 64x64 LDS tiles, both sides coalesced
__global__ __launch_bounds__(256) void transpose_w(
    const float* __restrict__ Wq, const float* __restrict__ Wk,
    const float* __restrict__ Wv, const float* __restrict__ Wo,
    float* __restrict__ wt_base) {
  __shared__ float tile[64][65];
  int m = blockIdx.y;
  const float* W = (m == 0) ? Wq : (m == 1) ? Wk : (m == 2) ? Wv : Wo;
  float* WT = wt_base + (size_t)m * HIDDEN * HIDDEN;
  int ti = blockIdx.x >> 4, tj = blockIdx.x & 15;
  int o0 = ti * 64, k0 = tj * 64;
  int tx = threadIdx.x & 63, ty0 = threadIdx.x >> 6;
#pragma unroll
  for (int r = 0; r < 16; ++r) {
    int row = ty0 + r * 4;
    tile[row][tx] = W[(size_t)(o0 + row) * HIDDEN + k0 + tx];
  }
  __syncthreads();
#pragma unroll
  for (int r = 0; r < 16; ++r) {
    int row = ty0 + r * 4;
    WT[(size_t)(k0 + row) * HIDDEN + o0 + tx] = tile[tx][row];
  }
}

// out[b][o] += sum_k x[b][k] * WT[k][o]; lane = o (coalesced W reads),
// x staged in LDS, k-split via blockIdx.z, atomic merge onto bias.
__device__ __forceinline__ void gemv_body(const float* __restrict__ x,
                                          const float* __restrict__ WT,
                                          float* __restrict__ out,
                                          int o0, int k0) {
  __shared__ __align__(16) float xs[BATCH][64];
  int t = threadIdx.x;
  // stage x[0..31][k0..k0+63]
#pragma unroll
  for (int idx = t; idx < BATCH * 64; idx += 256) {
    int b = idx >> 6, kk = idx & 63;
    xs[b][kk] = x[(size_t)b * HIDDEN + k0 + kk];
  }
  __syncthreads();
  float acc[BATCH];
#pragma unroll
  for (int b = 0; b < BATCH; ++b) acc[b] = 0.f;
  for (int kk4 = 0; kk4 < 16; ++kk4) {
    int kk = kk4 * 4;
    float w0 = WT[(size_t)(k0 + kk + 0) * HIDDEN + o0 + t];
    float w1 = WT[(size_t)(k0 + kk + 1) * HIDDEN + o0 + t];
    float w2 = WT[(size_t)(k0 + kk + 2) * HIDDEN + o0 + t];
    float w3 = WT[(size_t)(k0 + kk + 3) * HIDDEN + o0 + t];
#pragma unroll
    for (int b = 0; b < BATCH; ++b) {
      float4 xv = *(const float4*)&xs[b][kk];
      float a = acc[b];
      a = fmaf(xv.x, w0, a);
      a = fmaf(xv.y, w1, a);
      a = fmaf(xv.z, w2, a);
      a = fmaf(xv.w, w3, a);
      acc[b] = a;
    }
  }
#pragma unroll
  for (int b = 0; b < BATCH; ++b)
    unsafeAtomicAdd(&out[(size_t)b * HIDDEN + o0 + t], acc[b]);
}

__global__ __launch_bounds__(256) void gemv_qkv(
    const float* __restrict__ xq, const float* __restrict__ xk,
    const float* __restrict__ xv, const float* __restrict__ wt_base,
    float* __restrict__ outq, float* __restrict__ outk,
    float* __restrict__ outv) {
  const float* x; const float* WT; float* out;
  if (blockIdx.y == 0)      { x = xq; WT = wt_base;                        out = outq; }
  else if (blockIdx.y == 1) { x = xk; WT = wt_base + 1 * HIDDEN * HIDDEN;  out = outk; }
  else                      { x = xv; WT = wt_base + 2 * HIDDEN * HIDDEN;  out = outv; }
  gemv_body(x, WT, out, blockIdx.x * 256, blockIdx.z * 64);
}

__global__ __launch_bounds__(256) void gemv_o(
    const float* __restrict__ x, const float* __restrict__ wt_base,
    float* __restrict__ out) {
  gemv_body(x, wt_base + (size_t)3 * HIDDEN * HIDDEN, out,
            blockIdx.x * 256, blockIdx.z * 64);
}

// flash-decode: lane = (row-group rg 0..3, d-group qg 0..15); every global
// load is 1 KB contiguous per wave. Dot via 4-step butterfly in 16-lane groups.
__global__ __launch_bounds__(256) void attn_decode(
    const float* __restrict__ prev_key, const float* __restrict__ prev_value,
    const float* __restrict__ q_ws, const float* __restrict__ k_ws,
    const float* __restrict__ v_ws, const int* __restrict__ order,
    const int* __restrict__ mask, float* __restrict__ part_m,
    float* __restrict__ part_l, float* __restrict__ part_acc) {
  int split = blockIdx.x;           // 0..7
  int head  = blockIdx.y;           // 0..511 = b*16+h
  int b = head >> 4, h = head & 15;
  int t = threadIdx.x;
  int w = t >> 6, lane = t & 63;
  int rg = lane >> 4, qg = lane & 15;
  int bo = order[b];
  int s0 = split * SCHUNK;

  __shared__ float sc[SCHUNK];
  __shared__ float msk[SCHUNK];
  __shared__ float red_m[4];
  __shared__ float red_l[4];
  __shared__ __align__(16) float vred[4][HDIM];

  // mask chunk -> LDS (additive form)
  msk[t]       = -FMAX * (float)mask[s0 + t];
  msk[t + 256] = -FMAX * (float)mask[s0 + t + 256];

  // q fragment (scaled) in registers: lane qg holds q[d=qg*4..qg*4+3]
  float4 qs = *(const float4*)(q_ws + (size_t)b * HIDDEN + h * HDIM + (qg << 2));
  qs.x *= SCALING; qs.y *= SCALING; qs.z *= SCALING; qs.w *= SCALING;

  size_t kvbase = (size_t)(bo * NHEADS + h) * PREV * HDIM;
  const float* kws_row = k_ws + (size_t)b * HIDDEN + h * HDIM;
  const float* vws_row = v_ws + (size_t)b * HIDDEN + h * HDIM;
  __syncthreads();

  // ---- scores: wave w owns rows [w*128, w*128+128), 4 rows/iter ----
  for (int it = 0; it < 32; ++it) {
    int r = w * 128 + it * 4 + rg;
    int s = s0 + r;
    const float* kp = (s < PREV) ? (prev_key + kvbase + (size_t)s * HDIM)
                                 : kws_row;
    float4 kv = *(const float4*)(kp + (qg << 2));
    float d = kv.x * qs.x;
    d = fmaf(kv.y, qs.y, d);
    d = fmaf(kv.z, qs.z, d);
    d = fmaf(kv.w, qs.w, d);
    d += __shfl_xor(d, 1);
    d += __shfl_xor(d, 2);
    d += __shfl_xor(d, 4);
    d += __shfl_xor(d, 8);
    if (qg == 0) sc[r] = d + msk[r];
  }
  __syncthreads();

  // ---- block max ----
  float m = fmaxf(sc[t], sc[t + 256]);
#pragma unroll
  for (int off = 32; off >= 1; off >>= 1) m = fmaxf(m, __shfl_xor(m, off));
  if (lane == 0) red_m[w] = m;
  __syncthreads();
  m = fmaxf(fmaxf(red_m[0], red_m[1]), fmaxf(red_m[2], red_m[3]));

  // ---- exp + sum ----
  float e0 = __expf(sc[t] - m);
  float e1 = __expf(sc[t + 256] - m);
  sc[t] = e0; sc[t + 256] = e1;
  float lp = e0 + e1;
#pragma unroll
  for (int off = 32; off >= 1; off >>= 1) lp += __shfl_xor(lp, off);
  if (lane == 0) red_l[w] = lp;
  __syncthreads();
  float lb = (red_l[0] + red_l[1]) + (red_l[2] + red_l[3]);

  // ---- V accumulate: same lane layout, 4 rows/iter ----
  float4 av = {0.f, 0.f, 0.f, 0.f};
  for (int it = 0; it < 32; ++it) {
    int r = w * 128 + it * 4 + rg;
    int s = s0 + r;
    const float* vp = (s < PREV) ? (prev_value + kvbase + (size_t)s * HDIM)
                                 : vws_row;
    float4 vv = *(const float4*)(vp + (qg << 2));
    float wgt = sc[r];
    av.x = fmaf(wgt, vv.x, av.x);
    av.y = fmaf(wgt, vv.y, av.y);
    av.z = fmaf(wgt, vv.z, av.z);
    av.w = fmaf(wgt, vv.w, av.w);
  }
  // reduce across the 4 row-groups (lanes differing in bits 4..5)
#pragma unroll
  for (int off = 16; off <= 32; off <<= 1) {
    av.x += __shfl_xor(av.x, off);
    av.y += __shfl_xor(av.y, off);
    av.z += __shfl_xor(av.z, off);
    av.w += __shfl_xor(av.w, off);
  }
  if (rg == 0) *(float4*)&vred[w][qg << 2] = av;
  __syncthreads();
  if (t < HDIM) {
    float tot = (vred[0][t] + vred[1][t]) + (vred[2][t] + vred[3][t]);
    part_acc[((size_t)head * NSPLIT + split) * HDIM + t] = tot;
  }
  if (t == 0) {
    part_m[head * NSPLIT + split] = m;
    part_l[head * NSPLIT + split] = lb;
  }
}

__global__ __launch_bounds__(64) void attn_combine(
    const float* __restrict__ part_m, const float* __restrict__ part_l,
    const float* __restrict__ part_acc, float* __restrict__ attn) {
  int head = blockIdx.x;
  int d = threadIdx.x;
  float m = -FMAX;
#pragma unroll
  for (int i = 0; i < NSPLIT; ++i) m = fmaxf(m, part_m[head * NSPLIT + i]);
  float L = 0.f, o = 0.f;
#pragma unroll
  for (int i = 0; i < NSPLIT; ++i) {
    float w = __expf(part_m[head * NSPLIT + i] - m);
    L = fmaf(w, part_l[head * NSPLIT + i], L);
    o = fmaf(w, part_acc[((size_t)head * NSPLIT + i) * HDIM + d], o);
  }
  int b = head >> 4, h = head & 15;
  attn[(size_t)b * HIDDEN + h * HDIM + d] = o / L;
}

extern "C" void kernel_launch(void* const* d_in, const int* in_sizes, int n_in,
                              void* d_out, int out_size, void* d_ws, size_t ws_size,
                              hipStream_t stream) {
  const float* qx    = (const float*)d_in[0];
  const float* kx    = (const float*)d_in[1];
  const float* vx    = (const float*)d_in[2];
  const int*   mask  = (const int*)d_in[3];
  const int*   order = (const int*)d_in[4];
  const float* pk    = (const float*)d_in[5];
  const float* pv    = (const float*)d_in[6];
  const float* Wq    = (const float*)d_in[7];
  const float* bq    = (const float*)d_in[8];
  const float* Wk    = (const float*)d_in[9];
  const float* bk    = (const float*)d_in[10];
  const float* Wv    = (const float*)d_in[11];
  const float* bv    = (const float*)d_in[12];
  const float* Wo    = (const float*)d_in[13];
  const float* bo    = (const float*)d_in[14];
  float* out = (float*)d_out;
  float* ws  = (float*)d_ws;

  float* wt      = ws + WT_OFF;
  float* q_ws    = ws + Q_OFF;
  float* k_ws    = ws + K_OFF;
  float* v_ws    = ws + V_OFF;
  float* attn_ws = ws + ATTN_OFF;
  float* pm      = ws + PM_OFF;
  float* pl      = ws + PL_OFF;
  float* pacc    = ws + PACC_OFF;

  // 1. bias seed (ws/d_out are poisoned before every call)
  hipLaunchKernelGGL(init_bias, dim3(128), dim3(256), 0, stream,
                     bq, bk, bv, bo, q_ws, k_ws, v_ws, out);
  // 2. transpose all four weight matrices into ws
  hipLaunchKernelGGL(transpose_w, dim3(256, 4), dim3(256), 0, stream,
                     Wq, Wk, Wv, Wo, wt);
  // 3. QKV projections (coalesced GEMV, k-split=16)
  hipLaunchKernelGGL(gemv_qkv, dim3(4, 3, 16), dim3(256), 0, stream,
                     qx, kx, vx, wt, q_ws, k_ws, v_ws);
  // 4. flash-decode attention over 8 S-splits
  hipLaunchKernelGGL(attn_decode, dim3(NSPLIT, 512), dim3(256), 0, stream,
                     pk, pv, q_ws, k_ws, v_ws, order, mask, pm, pl, pacc);
  // 5. merge splits
  hipLaunchKernelGGL(attn_combine, dim3(512), dim3(64), 0, stream,
                     pm, pl, pacc, attn_ws);
  // 6. output projection
  hipLaunchKernelGGL(gemv_o, dim3(4, 1, 16), dim3(256), 0, stream,
                     attn_ws, wt, out);
}